// Round 2
// baseline (470.548 us; speedup 1.0000x reference)
//
#include <hip/hip_runtime.h>
#include <hip/hip_bf16.h>

// Problem constants
#define B_ 2
#define S_ 2048
#define D_ 256
#define H_ 8
#define E_ 256
#define F_ 1024

typedef __attribute__((ext_vector_type(8))) __bf16 b16x8;
typedef __attribute__((ext_vector_type(4))) __bf16 b16x4;
typedef __attribute__((ext_vector_type(4))) float f32x4;

__device__ inline float wred_sum(float v) {
#pragma unroll
  for (int o = 32; o > 0; o >>= 1) v += __shfl_xor(v, o);
  return v;
}
__device__ inline float wred_max(float v) {
#pragma unroll
  for (int o = 32; o > 0; o >>= 1) v = fmaxf(v, __shfl_xor(v, o));
  return v;
}

// ---------------- LayerNorm (+cast to bf16): one row of 256 per wave ----------------
__global__ __launch_bounds__(256) void ln_cast_kernel(
    const float* __restrict__ x, const float* __restrict__ scale,
    const float* __restrict__ bias, __bf16* __restrict__ out) {
  const int row = blockIdx.x * 4 + (threadIdx.x >> 6);
  const int lane = threadIdx.x & 63;
  const float4 v = *(const float4*)(x + (size_t)row * D_ + lane * 4);
  float s = v.x + v.y + v.z + v.w;
  float q = v.x * v.x + v.y * v.y + v.z * v.z + v.w * v.w;
  s = wred_sum(s);
  q = wred_sum(q);
  const float mean = s * (1.0f / D_);
  const float var = q * (1.0f / D_) - mean * mean;
  const float rstd = rsqrtf(var + 1e-6f);
  const float4 sc = *(const float4*)(scale + lane * 4);
  const float4 bi = *(const float4*)(bias + lane * 4);
  b16x4 o;
  o[0] = (__bf16)((v.x - mean) * rstd * sc.x + bi.x);
  o[1] = (__bf16)((v.y - mean) * rstd * sc.y + bi.y);
  o[2] = (__bf16)((v.z - mean) * rstd * sc.z + bi.z);
  o[3] = (__bf16)((v.w - mean) * rstd * sc.w + bi.w);
  *(b16x4*)(out + (size_t)row * D_ + lane * 4) = o;
}

// ---------------- Weight transpose-cast: outT[c][r] = in[r][c], f32 -> bf16 ----------------
__device__ inline void tr1(const float* __restrict__ in, __bf16* __restrict__ out,
                           int R, int C, size_t o) {
  int r = (int)(o % R), c = (int)(o / R);
  out[o] = (__bf16)in[(size_t)r * C + c];
}
__global__ __launch_bounds__(256) void tcast_all(
    const float* wq, const float* wk, const float* wv, const float* wo,
    const float* w1, const float* w2, __bf16* wqT, __bf16* wkT, __bf16* wvT,
    __bf16* woT, __bf16* w1T, __bf16* w2T) {
  size_t o = (size_t)blockIdx.x * 256 + threadIdx.x;
  // segments: 3x 524288 (qkv), 524288 (wo), 2x 262144 (w1,w2) = 2621440 total
  if (o < 524288) tr1(wq, wqT, 256, 2048, o);
  else if (o < 1048576) tr1(wk, wkT, 256, 2048, o - 524288);
  else if (o < 1572864) tr1(wv, wvT, 256, 2048, o - 1048576);
  else if (o < 2097152) tr1(wo, woT, 2048, 256, o - 1572864);
  else if (o < 2359296) tr1(w1, w1T, 256, 1024, o - 2097152);
  else if (o < 2621440) tr1(w2, w2T, 1024, 256, o - 2359296);
}

// ---------------- Row softmax, in place, row length 2048 ----------------
__global__ __launch_bounds__(256) void softmax_kernel(float* __restrict__ p) {
  float* row = p + (size_t)blockIdx.x * 2048;
  const int t = threadIdx.x;
  const int wid = t >> 6, lane = t & 63;
  float4 a = ((float4*)row)[t];
  float4 b = ((float4*)row)[t + 256];
  float mx = fmaxf(fmaxf(fmaxf(a.x, a.y), fmaxf(a.z, a.w)),
                   fmaxf(fmaxf(b.x, b.y), fmaxf(b.z, b.w)));
  mx = wred_max(mx);
  __shared__ float red[4];
  if (lane == 0) red[wid] = mx;
  __syncthreads();
  mx = fmaxf(fmaxf(red[0], red[1]), fmaxf(red[2], red[3]));
  a.x = __expf(a.x - mx); a.y = __expf(a.y - mx);
  a.z = __expf(a.z - mx); a.w = __expf(a.w - mx);
  b.x = __expf(b.x - mx); b.y = __expf(b.y - mx);
  b.z = __expf(b.z - mx); b.w = __expf(b.w - mx);
  float s = a.x + a.y + a.z + a.w + b.x + b.y + b.z + b.w;
  s = wred_sum(s);
  __syncthreads();
  if (lane == 0) red[wid] = s;
  __syncthreads();
  s = red[0] + red[1] + red[2] + red[3];
  const float inv = 1.0f / s;
  a.x *= inv; a.y *= inv; a.z *= inv; a.w *= inv;
  b.x *= inv; b.y *= inv; b.z *= inv; b.w *= inv;
  ((float4*)row)[t] = a;
  ((float4*)row)[t + 256] = b;
}

__device__ inline float gelu_f(float u) {
  const float c = 0.7978845608028654f;  // sqrt(2/pi)
  float t = tanhf(c * (u + 0.044715f * u * u * u));
  return 0.5f * u * (1.0f + t);
}

// ---------------- NT GEMM: C = A(MxK) * Bt(NxK)^T, bf16 MFMA, fp32 acc ----------------
// EPI: 0=q/k->(h,s,e)+bias   1=v->(h,e,s)+bias   2=scores*1/16->f32
//      3=pv->val(s,h*e)      4=f32 out = resid + acc + bias (N=256)
//      5=fc1: gelu(acc+bias)->bf16 (N=1024)
// (per-b launches: M=2048, so the b=grow>>11 terms fold to 0)
#define BM 128
#define BN 128
#define BK 64

template <int EPI, typename TA>
__global__ __launch_bounds__(256) void gemm_nt(
    const TA* __restrict__ A, const __bf16* __restrict__ Bt,
    const float* __restrict__ bias, const float* __restrict__ resid,
    void* __restrict__ Cout, int K, long strideAz, long strideBz) {
  __shared__ __attribute__((aligned(16))) __bf16 As[BM * BK];
  __shared__ __attribute__((aligned(16))) __bf16 Bs[BN * BK];
  const int tid = threadIdx.x;
  const int lane = tid & 63;
  const int wid = tid >> 6;
  const int wr = wid >> 1, wc = wid & 1;
  const int m0 = blockIdx.y * BM, n0 = blockIdx.x * BN;
  const TA* Ab = A + (size_t)blockIdx.z * strideAz;
  const __bf16* Btb = Bt + (size_t)blockIdx.z * strideBz;

  f32x4 acc[4][4] = {};

  for (int k0 = 0; k0 < K; k0 += BK) {
    __syncthreads();
#pragma unroll
    for (int i = 0; i < 4; ++i) {
      const int cid = tid + i * 256;
      const int row = cid >> 3, ch = cid & 7;
      const int sw = ch ^ (row & 7);
      b16x8 av;
      const size_t aoff = (size_t)(m0 + row) * K + k0 + ch * 8;
      if constexpr (sizeof(TA) == 2) {
        av = *(const b16x8*)(Ab + aoff);
      } else {
        const float* ap = (const float*)Ab + aoff;
        const float4 f0 = *(const float4*)ap;
        const float4 f1 = *(const float4*)(ap + 4);
        av[0] = (__bf16)f0.x; av[1] = (__bf16)f0.y;
        av[2] = (__bf16)f0.z; av[3] = (__bf16)f0.w;
        av[4] = (__bf16)f1.x; av[5] = (__bf16)f1.y;
        av[6] = (__bf16)f1.z; av[7] = (__bf16)f1.w;
      }
      *(b16x8*)(As + row * BK + sw * 8) = av;
      const b16x8 bv = *(const b16x8*)(Btb + (size_t)(n0 + row) * K + k0 + ch * 8);
      *(b16x8*)(Bs + row * BK + sw * 8) = bv;
    }
    __syncthreads();
#pragma unroll
    for (int ks = 0; ks < 2; ++ks) {
      b16x8 af[4], bfr[4];
#pragma unroll
      for (int m = 0; m < 4; ++m) {
        const int r = wr * 64 + m * 16 + (lane & 15);
        const int ch = ks * 4 + (lane >> 4);
        const int sw = ch ^ (r & 7);
        af[m] = *(const b16x8*)(As + r * BK + sw * 8);
      }
#pragma unroll
      for (int n = 0; n < 4; ++n) {
        const int r = wc * 64 + n * 16 + (lane & 15);
        const int ch = ks * 4 + (lane >> 4);
        const int sw = ch ^ (r & 7);
        bfr[n] = *(const b16x8*)(Bs + r * BK + sw * 8);
      }
#pragma unroll
      for (int m = 0; m < 4; ++m)
#pragma unroll
        for (int n = 0; n < 4; ++n)
          acc[m][n] = __builtin_amdgcn_mfma_f32_16x16x32_bf16(af[m], bfr[n],
                                                              acc[m][n], 0, 0, 0);
    }
  }

  const int z = blockIdx.z;
#pragma unroll
  for (int m = 0; m < 4; ++m) {
    const int gr0 = m0 + wr * 64 + m * 16 + (lane >> 4) * 4;
#pragma unroll
    for (int n = 0; n < 4; ++n) {
      const int gc = n0 + wc * 64 + n * 16 + (lane & 15);
#pragma unroll
      for (int r = 0; r < 4; ++r) {
        float v = acc[m][n][r];
        const int grow = gr0 + r;
        if constexpr (EPI == 0 || EPI == 1) {
          v += bias[gc];
          const int b = grow >> 11, s = grow & 2047;
          const int h = gc >> 8, e = gc & 255;
          __bf16* o = (__bf16*)Cout;
          if constexpr (EPI == 0)
            o[(((size_t)(b * H_ + h) * S_) + s) * E_ + e] = (__bf16)v;
          else
            o[(((size_t)(b * H_ + h) * E_) + e) * S_ + s] = (__bf16)v;
        } else if constexpr (EPI == 2) {
          ((float*)Cout)[(size_t)z * S_ * S_ + (size_t)grow * S_ + gc] = v * 0.0625f;
        } else if constexpr (EPI == 3) {
          const int b = z >> 3, h = z & 7;
          ((__bf16*)Cout)[((size_t)b * S_ + grow) * (H_ * E_) + h * E_ + gc] = (__bf16)v;
        } else if constexpr (EPI == 4) {
          const size_t o = (size_t)grow * D_ + gc;
          ((float*)Cout)[o] = resid[o] + v + bias[gc];
        } else {  // 5: fc1 gelu
          ((__bf16*)Cout)[(size_t)grow * F_ + gc] = (__bf16)gelu_f(v + bias[gc]);
        }
      }
    }
  }
}

extern "C" void kernel_launch(void* const* d_in, const int* in_sizes, int n_in,
                              void* d_out, int out_size, void* d_ws, size_t ws_size,
                              hipStream_t stream) {
  (void)in_sizes; (void)n_in; (void)out_size; (void)ws_size;
  const float* x    = (const float*)d_in[0];
  const float* ln1s = (const float*)d_in[1];
  const float* ln1b = (const float*)d_in[2];
  const float* wq   = (const float*)d_in[3];
  const float* bq   = (const float*)d_in[4];
  const float* wk   = (const float*)d_in[5];
  const float* bk   = (const float*)d_in[6];
  const float* wv   = (const float*)d_in[7];
  const float* bv   = (const float*)d_in[8];
  const float* wo   = (const float*)d_in[9];
  const float* bo   = (const float*)d_in[10];
  const float* ln2s = (const float*)d_in[11];
  const float* ln2b = (const float*)d_in[12];
  const float* w1   = (const float*)d_in[13];
  const float* b1   = (const float*)d_in[14];
  const float* w2   = (const float*)d_in[15];
  const float* b2   = (const float*)d_in[16];

  float* out  = (float*)d_out;                           // (B,S,D) = 4 MB, doubles as x2
  float* attn = (float*)d_out + (size_t)B_ * S_ * D_;    // (B,H,S,S) f32

  // ---- workspace: 24 MB total (tight budget; ws_size was the round-1 failure) ----
  char* ws = (char*)d_ws;
  __bf16* xln = (__bf16*)(ws);                           // [0,2MB)
  __bf16* wqT = (__bf16*)(ws + (2ull << 20));            // 1 MB each
  __bf16* wkT = (__bf16*)(ws + (3ull << 20));
  __bf16* wvT = (__bf16*)(ws + (4ull << 20));
  __bf16* woT = (__bf16*)(ws + (5ull << 20));
  __bf16* w1T = (__bf16*)(ws + (6ull << 20));            // 0.5 MB
  __bf16* w2T = (__bf16*)(ws + (6ull << 20) + (512ull << 10));
  __bf16* bufA = (__bf16*)(ws + (8ull << 20));           // [8,16MB): q_b / vt_b / hbf
  __bf16* bufB = (__bf16*)(ws + (16ull << 20));          // [16,24MB): k_b / val_b

  const dim3 blk(256);

  tcast_all<<<10240, blk, 0, stream>>>(wq, wk, wv, wo, w1, w2,
                                       wqT, wkT, wvT, woT, w1T, w2T);
  ln_cast_kernel<<<1024, blk, 0, stream>>>(x, ln1s, ln1b, xln);

  for (int b = 0; b < B_; ++b) {
    const __bf16* xln_b = xln + (size_t)b * S_ * D_;
    float* attn_b = attn + (size_t)b * H_ * S_ * S_;
    const float* x_b = x + (size_t)b * S_ * D_;
    float* out_b = out + (size_t)b * S_ * D_;

    // q_b, k_b: M=2048, N=2048, K=256 -> (h,s,e)
    gemm_nt<0, __bf16><<<dim3(16, 16, 1), blk, 0, stream>>>(xln_b, wqT, bq, nullptr, bufA, 256, 0, 0);
    gemm_nt<0, __bf16><<<dim3(16, 16, 1), blk, 0, stream>>>(xln_b, wkT, bk, nullptr, bufB, 256, 0, 0);

    // scores_b = Q K^T / 16 : per h, M=N=2048, K=256 -> attn_b (f32)
    gemm_nt<2, __bf16><<<dim3(16, 16, 8), blk, 0, stream>>>(
        bufA, bufB, nullptr, nullptr, attn_b, 256, (long)S_ * E_, (long)S_ * E_);

    softmax_kernel<<<H_ * S_, blk, 0, stream>>>(attn_b);

    // vt_b: M=2048, N=2048, K=256 -> (h,e,s)   (q_b in bufA now dead)
    gemm_nt<1, __bf16><<<dim3(16, 16, 1), blk, 0, stream>>>(xln_b, wvT, bv, nullptr, bufA, 256, 0, 0);

    // PV_b: per h, M=2048, N=256(e), K=2048 -> val_b (s, h*e)  (k_b in bufB dead)
    gemm_nt<3, float><<<dim3(2, 16, 8), blk, 0, stream>>>(
        attn_b, bufA, nullptr, nullptr, bufB, 2048, (long)S_ * S_, (long)E_ * S_);

    // WO_b: out_b(x2) = x_b + val_b @ wo + bo : M=2048, N=256, K=2048
    gemm_nt<4, __bf16><<<dim3(2, 16, 1), blk, 0, stream>>>(bufB, woT, bo, x_b, out_b, 2048, 0, 0);
  }

  // ln2 over x2 (held in out region)
  ln_cast_kernel<<<1024, blk, 0, stream>>>(out, ln2s, ln2b, xln);

  // FC1: h = gelu(xln2 @ w1 + b1) : M=4096, N=1024, K=256 -> bufA
  gemm_nt<5, __bf16><<<dim3(8, 32, 1), blk, 0, stream>>>(xln, w1T, b1, nullptr, bufA, 256, 0, 0);

  // FC2: out = x2 + h @ w2 + b2 : M=4096, N=256, K=1024 (in-place RMW on out)
  gemm_nt<4, __bf16><<<dim3(2, 32, 1), blk, 0, stream>>>(bufA, w2T, b2, out, out, 1024, 0, 0);
}

// Round 3
// 430.427 us; speedup vs baseline: 1.0932x; 1.0932x over previous
//
#include <hip/hip_runtime.h>
#include <hip/hip_bf16.h>

// Problem constants
#define B_ 2
#define S_ 2048
#define D_ 256
#define H_ 8
#define E_ 256
#define F_ 1024

typedef __attribute__((ext_vector_type(8))) __bf16 b16x8;
typedef __attribute__((ext_vector_type(4))) __bf16 b16x4;
typedef __attribute__((ext_vector_type(4))) float f32x4;

__device__ inline float wred_sum(float v) {
#pragma unroll
  for (int o = 32; o > 0; o >>= 1) v += __shfl_xor(v, o);
  return v;
}

// ---------------- LayerNorm (+cast to bf16): one row of 256 per wave ----------------
__global__ __launch_bounds__(256) void ln_cast_kernel(
    const float* __restrict__ x, const float* __restrict__ scale,
    const float* __restrict__ bias, __bf16* __restrict__ out) {
  const int row = blockIdx.x * 4 + (threadIdx.x >> 6);
  const int lane = threadIdx.x & 63;
  const float4 v = *(const float4*)(x + (size_t)row * D_ + lane * 4);
  float s = v.x + v.y + v.z + v.w;
  float q = v.x * v.x + v.y * v.y + v.z * v.z + v.w * v.w;
  s = wred_sum(s);
  q = wred_sum(q);
  const float mean = s * (1.0f / D_);
  const float var = q * (1.0f / D_) - mean * mean;
  const float rstd = rsqrtf(var + 1e-6f);
  const float4 sc = *(const float4*)(scale + lane * 4);
  const float4 bi = *(const float4*)(bias + lane * 4);
  b16x4 o;
  o[0] = (__bf16)((v.x - mean) * rstd * sc.x + bi.x);
  o[1] = (__bf16)((v.y - mean) * rstd * sc.y + bi.y);
  o[2] = (__bf16)((v.z - mean) * rstd * sc.z + bi.z);
  o[3] = (__bf16)((v.w - mean) * rstd * sc.w + bi.w);
  *(b16x4*)(out + (size_t)row * D_ + lane * 4) = o;
}

// ---------------- Coalesced weight transpose-cast via LDS, + l zeroing ----------------
// Segments of 64x64 tiles: wq,wk,wv (256x2048:128 ea), wo (2048x256:128),
// w1 (256x1024:64), w2 (1024x256:64) = 640 blocks; +32 blocks zero l (32768 f32).
__global__ __launch_bounds__(256) void trans_cast(
    const float* wq, const float* wk, const float* wv, const float* wo,
    const float* w1, const float* w2, __bf16* wqT, __bf16* wkT, __bf16* wvT,
    __bf16* woT, __bf16* w1T, __bf16* w2T, float* l_all) {
  __shared__ float lds[64][65];
  int bid = blockIdx.x;
  const int t = threadIdx.x;
  if (bid >= 640) {  // zero l
    ((float4*)l_all)[(bid - 640) * 256 + t] = float4{0.f, 0.f, 0.f, 0.f};
    return;
  }
  const float* in;
  __bf16* out;
  int R, C, tidx;
  if (bid < 128) { in = wq; out = wqT; R = 256; C = 2048; tidx = bid; }
  else if (bid < 256) { in = wk; out = wkT; R = 256; C = 2048; tidx = bid - 128; }
  else if (bid < 384) { in = wv; out = wvT; R = 256; C = 2048; tidx = bid - 256; }
  else if (bid < 512) { in = wo; out = woT; R = 2048; C = 256; tidx = bid - 384; }
  else if (bid < 576) { in = w1; out = w1T; R = 256; C = 1024; tidx = bid - 512; }
  else { in = w2; out = w2T; R = 1024; C = 256; tidx = bid - 576; }
  const int tiles_c = C >> 6;
  const int tr = tidx / tiles_c, tc = tidx % tiles_c;
  // load 64x64 f32 tile, coalesced rows
  const int r = t >> 2, cq = t & 3;
  const float* base = in + (size_t)(tr * 64 + r) * C + tc * 64 + cq * 16;
#pragma unroll
  for (int i = 0; i < 4; ++i) {
    const float4 v = ((const float4*)base)[i];
    lds[r][cq * 16 + i * 4 + 0] = v.x;
    lds[r][cq * 16 + i * 4 + 1] = v.y;
    lds[r][cq * 16 + i * 4 + 2] = v.z;
    lds[r][cq * 16 + i * 4 + 3] = v.w;
  }
  __syncthreads();
  // write transposed: out[C][R]; out-row oc = tc*64 + (t>>2)
  const int oc = t >> 2;
  __bf16* ob = out + (size_t)(tc * 64 + oc) * R + tr * 64 + cq * 16;
  b16x8 o0, o1;
#pragma unroll
  for (int i = 0; i < 8; ++i) o0[i] = (__bf16)lds[cq * 16 + i][oc];
#pragma unroll
  for (int i = 0; i < 8; ++i) o1[i] = (__bf16)lds[cq * 16 + 8 + i][oc];
  ((b16x8*)ob)[0] = o0;
  ((b16x8*)ob)[1] = o1;
}

__device__ inline float gelu_f(float u) {
  const float c = 0.7978845608028654f;  // sqrt(2/pi)
  float t = tanhf(c * (u + 0.044715f * u * u * u));
  return 0.5f * u * (1.0f + t);
}

// ---------------- NT GEMM: C = A(MxK) * Bt(NxK)^T, bf16 MFMA, fp32 acc ----------------
// EPI: 1=v->(h,e,s)+bias          2=scores: write exp(s/16) + atomicAdd row sums (l in `resid`)
//      5=fc1: gelu(acc+bias)->bf16 (N=1024)
//      6=merged qk -> (h,s,e)+bias; sel=gc>>11 picks q/k half (bias2 in `resid`)
//      7=split-K partial f32 -> pbuf[z][M][256]
#define BM 128
#define BN 128
#define BK 64

template <int EPI, typename TA>
__global__ __launch_bounds__(256) void gemm_nt(
    const TA* __restrict__ A, const __bf16* __restrict__ Bt,
    const float* __restrict__ bias, const float* __restrict__ resid,
    void* __restrict__ Cout, int K, int lda, int ldb, long strideAz, long strideBz) {
  __shared__ __attribute__((aligned(16))) __bf16 As[BM * BK];
  __shared__ __attribute__((aligned(16))) __bf16 Bs[BN * BK];
  const int tid = threadIdx.x;
  const int lane = tid & 63;
  const int wid = tid >> 6;
  const int wr = wid >> 1, wc = wid & 1;
  const int m0 = blockIdx.y * BM, n0 = blockIdx.x * BN;
  const TA* Ab = A + (size_t)blockIdx.z * strideAz;
  const __bf16* Btb = Bt + (size_t)blockIdx.z * strideBz;

  f32x4 acc[4][4] = {};

  for (int k0 = 0; k0 < K; k0 += BK) {
    __syncthreads();
#pragma unroll
    for (int i = 0; i < 4; ++i) {
      const int cid = tid + i * 256;
      const int row = cid >> 3, ch = cid & 7;
      const int sw = ch ^ (row & 7);
      b16x8 av;
      const size_t aoff = (size_t)(m0 + row) * lda + k0 + ch * 8;
      if constexpr (sizeof(TA) == 2) {
        av = *(const b16x8*)(Ab + aoff);
      } else {
        const float* ap = (const float*)Ab + aoff;
        const float4 f0 = *(const float4*)ap;
        const float4 f1 = *(const float4*)(ap + 4);
        av[0] = (__bf16)f0.x; av[1] = (__bf16)f0.y;
        av[2] = (__bf16)f0.z; av[3] = (__bf16)f0.w;
        av[4] = (__bf16)f1.x; av[5] = (__bf16)f1.y;
        av[6] = (__bf16)f1.z; av[7] = (__bf16)f1.w;
      }
      *(b16x8*)(As + row * BK + sw * 8) = av;
      const b16x8 bv = *(const b16x8*)(Btb + (size_t)(n0 + row) * ldb + k0 + ch * 8);
      *(b16x8*)(Bs + row * BK + sw * 8) = bv;
    }
    __syncthreads();
#pragma unroll
    for (int ks = 0; ks < 2; ++ks) {
      b16x8 af[4], bfr[4];
#pragma unroll
      for (int m = 0; m < 4; ++m) {
        const int r = wr * 64 + m * 16 + (lane & 15);
        const int ch = ks * 4 + (lane >> 4);
        const int sw = ch ^ (r & 7);
        af[m] = *(const b16x8*)(As + r * BK + sw * 8);
      }
#pragma unroll
      for (int n = 0; n < 4; ++n) {
        const int r = wc * 64 + n * 16 + (lane & 15);
        const int ch = ks * 4 + (lane >> 4);
        const int sw = ch ^ (r & 7);
        bfr[n] = *(const b16x8*)(Bs + r * BK + sw * 8);
      }
#pragma unroll
      for (int m = 0; m < 4; ++m)
#pragma unroll
        for (int n = 0; n < 4; ++n)
          acc[m][n] = __builtin_amdgcn_mfma_f32_16x16x32_bf16(af[m], bfr[n],
                                                              acc[m][n], 0, 0, 0);
    }
  }

  const int z = blockIdx.z;

  if constexpr (EPI == 2) {
    // fused exp + row-sum epilogue; Cout = attn_b (f32), resid = l_b
    float* lrow = const_cast<float*>(resid) + (size_t)z * S_;
    float* ab = (float*)Cout + (size_t)z * S_ * S_;
#pragma unroll
    for (int m = 0; m < 4; ++m) {
#pragma unroll
      for (int r = 0; r < 4; ++r) {
        const int grow = m0 + wr * 64 + m * 16 + (lane >> 4) * 4 + r;
        float srow = 0.f;
#pragma unroll
        for (int n = 0; n < 4; ++n) {
          const int gc = n0 + wc * 64 + n * 16 + (lane & 15);
          const float p = __expf(acc[m][n][r] * 0.0625f);
          ab[(size_t)grow * S_ + gc] = p;
          srow += p;
        }
        srow += __shfl_xor(srow, 1);
        srow += __shfl_xor(srow, 2);
        srow += __shfl_xor(srow, 4);
        srow += __shfl_xor(srow, 8);
        if ((lane & 15) == 0) atomicAdd(lrow + grow, srow);
      }
    }
    return;
  }

#pragma unroll
  for (int m = 0; m < 4; ++m) {
    const int gr0 = m0 + wr * 64 + m * 16 + (lane >> 4) * 4;
#pragma unroll
    for (int n = 0; n < 4; ++n) {
      const int gc = n0 + wc * 64 + n * 16 + (lane & 15);
#pragma unroll
      for (int r = 0; r < 4; ++r) {
        float v = acc[m][n][r];
        const int grow = gr0 + r;
        if constexpr (EPI == 1) {
          v += bias[gc];
          const int h = gc >> 8, e = gc & 255;
          ((__bf16*)Cout)[((size_t)h * E_ + e) * S_ + grow] = (__bf16)v;
        } else if constexpr (EPI == 5) {
          ((__bf16*)Cout)[(size_t)grow * F_ + gc] = (__bf16)gelu_f(v + bias[gc]);
        } else if constexpr (EPI == 6) {
          const int sel = gc >> 11, gcl = gc & 2047;
          v += (sel ? resid : bias)[gcl];
          const int h = gcl >> 8, e = gcl & 255;
          __bf16* o = (__bf16*)Cout + (size_t)sel * 4194304;
          o[((size_t)h * S_ + grow) * E_ + e] = (__bf16)v;
        } else {  // 7: split-K partial
          ((float*)Cout)[((size_t)z * gridDim.y * BM + grow) * 256 + gc] = v;
        }
      }
    }
  }
}

// ---------------- Fused PV: normalize P~ in place + write attn + MFMA with V^T ----------------
// Block = 64 q-rows x 256 e-cols (full E -> exclusive row ownership). K = S = 2048.
__global__ __launch_bounds__(256) void pv_fused(
    float* __restrict__ attn_b, const float* __restrict__ l_b,
    const __bf16* __restrict__ vt_b, __bf16* __restrict__ val_b) {
  __shared__ __attribute__((aligned(16))) __bf16 As[64 * 64];    // 8 KB
  __shared__ __attribute__((aligned(16))) __bf16 Bs[256 * 64];   // 32 KB
  const int tid = threadIdx.x, lane = tid & 63, wid = tid >> 6;
  const int wr = wid >> 1, wc = wid & 1;  // wave tile 32 x 128
  const int m0 = blockIdx.x * 64;
  const int h = blockIdx.y;
  float* Ab = attn_b + (size_t)h * S_ * S_;
  const float* lb = l_b + (size_t)h * S_;
  const __bf16* Bb = vt_b + (size_t)h * E_ * S_;

  f32x4 acc[2][8] = {};

  for (int k0 = 0; k0 < S_; k0 += 64) {
    __syncthreads();
    // A: 64 rows x 64 cols f32 -> normalize, write back, cast to LDS
#pragma unroll
    for (int i = 0; i < 2; ++i) {
      const int cid = tid + i * 256;
      const int row = cid >> 3, ch = cid & 7;
      float* ap = Ab + (size_t)(m0 + row) * S_ + k0 + ch * 8;
      float4 f0 = ((float4*)ap)[0], f1 = ((float4*)ap)[1];
      const float inv = 1.0f / lb[m0 + row];
      f0.x *= inv; f0.y *= inv; f0.z *= inv; f0.w *= inv;
      f1.x *= inv; f1.y *= inv; f1.z *= inv; f1.w *= inv;
      ((float4*)ap)[0] = f0;
      ((float4*)ap)[1] = f1;
      b16x8 av;
      av[0] = (__bf16)f0.x; av[1] = (__bf16)f0.y;
      av[2] = (__bf16)f0.z; av[3] = (__bf16)f0.w;
      av[4] = (__bf16)f1.x; av[5] = (__bf16)f1.y;
      av[6] = (__bf16)f1.z; av[7] = (__bf16)f1.w;
      const int sw = ch ^ (row & 7);
      *(b16x8*)(As + row * 64 + sw * 8) = av;
    }
    // B: 256 rows x 64 cols bf16
#pragma unroll
    for (int i = 0; i < 8; ++i) {
      const int cid = tid + i * 256;
      const int row = cid >> 3, ch = cid & 7;
      const b16x8 bv = *(const b16x8*)(Bb + (size_t)row * S_ + k0 + ch * 8);
      const int sw = ch ^ (row & 7);
      *(b16x8*)(Bs + row * 64 + sw * 8) = bv;
    }
    __syncthreads();
#pragma unroll
    for (int ks = 0; ks < 2; ++ks) {
      b16x8 af[2], bfr[8];
#pragma unroll
      for (int m = 0; m < 2; ++m) {
        const int r = wr * 32 + m * 16 + (lane & 15);
        const int ch = ks * 4 + (lane >> 4);
        af[m] = *(const b16x8*)(As + r * 64 + (ch ^ (r & 7)) * 8);
      }
#pragma unroll
      for (int n = 0; n < 8; ++n) {
        const int r = wc * 128 + n * 16 + (lane & 15);
        const int ch = ks * 4 + (lane >> 4);
        bfr[n] = *(const b16x8*)(Bs + r * 64 + (ch ^ (r & 7)) * 8);
      }
#pragma unroll
      for (int m = 0; m < 2; ++m)
#pragma unroll
        for (int n = 0; n < 8; ++n)
          acc[m][n] = __builtin_amdgcn_mfma_f32_16x16x32_bf16(af[m], bfr[n],
                                                              acc[m][n], 0, 0, 0);
    }
  }

#pragma unroll
  for (int m = 0; m < 2; ++m) {
#pragma unroll
    for (int n = 0; n < 8; ++n) {
#pragma unroll
      for (int r = 0; r < 4; ++r) {
        const int grow = m0 + wr * 32 + m * 16 + (lane >> 4) * 4 + r;
        const int gc = wc * 128 + n * 16 + (lane & 15);
        val_b[(size_t)grow * 2048 + h * E_ + gc] = (__bf16)acc[m][n][r];
      }
    }
  }
}

// ---------------- out = resid + bias + sum_z pbuf[z] (N=256 cols) ----------------
__global__ __launch_bounds__(256) void reduce_addk(
    const float* __restrict__ pbuf, const float* __restrict__ resid,
    const float* __restrict__ bias, float* __restrict__ out, int mn4, int kz) {
  const int i = blockIdx.x * 256 + threadIdx.x;
  if (i >= mn4) return;
  float4 s = ((const float4*)resid)[i];
  const float4 bb = ((const float4*)bias)[i & 63];
  s.x += bb.x; s.y += bb.y; s.z += bb.z; s.w += bb.w;
  for (int z = 0; z < kz; ++z) {
    const float4 p = ((const float4*)pbuf)[(size_t)z * mn4 + i];
    s.x += p.x; s.y += p.y; s.z += p.z; s.w += p.w;
  }
  ((float4*)out)[i] = s;
}

extern "C" void kernel_launch(void* const* d_in, const int* in_sizes, int n_in,
                              void* d_out, int out_size, void* d_ws, size_t ws_size,
                              hipStream_t stream) {
  (void)in_sizes; (void)n_in; (void)out_size; (void)ws_size;
  const float* x    = (const float*)d_in[0];
  const float* ln1s = (const float*)d_in[1];
  const float* ln1b = (const float*)d_in[2];
  const float* wq   = (const float*)d_in[3];
  const float* bq   = (const float*)d_in[4];
  const float* wk   = (const float*)d_in[5];
  const float* bk   = (const float*)d_in[6];
  const float* wv   = (const float*)d_in[7];
  const float* bv   = (const float*)d_in[8];
  const float* wo   = (const float*)d_in[9];
  const float* bo   = (const float*)d_in[10];
  const float* ln2s = (const float*)d_in[11];
  const float* ln2b = (const float*)d_in[12];
  const float* w1   = (const float*)d_in[13];
  const float* b1   = (const float*)d_in[14];
  const float* w2   = (const float*)d_in[15];
  const float* b2   = (const float*)d_in[16];

  float* out  = (float*)d_out;                           // (B,S,D), doubles as x2
  float* attn = (float*)d_out + (size_t)B_ * S_ * D_;    // (B,H,S,S) f32

  // ---- workspace: 24 MB total ----
  char* ws = (char*)d_ws;
  __bf16* xln  = (__bf16*)(ws);                          // [0,2MB)
  __bf16* wqT  = (__bf16*)(ws + (2ull << 20));           // [2,3) — wkT must follow contiguously
  __bf16* wkT  = (__bf16*)(ws + (3ull << 20));           // [3,4)
  __bf16* wvT  = (__bf16*)(ws + (4ull << 20));           // [4,5)
  __bf16* woT  = (__bf16*)(ws + (5ull << 20));           // [5,6)
  __bf16* w1T  = (__bf16*)(ws + (6ull << 20));           // [6,6.5)
  __bf16* w2T  = (__bf16*)(ws + (6ull << 20) + (512ull << 10));  // [6.5,7)
  float*  l_all = (float*)(ws + (7ull << 20));           // [7,7.125) 32768 f32
  __bf16* bufA = (__bf16*)(ws + (8ull << 20));           // [8,16): q_b / vt_b / WO-pbuf / hbf
  __bf16* bufB = (__bf16*)(ws + (16ull << 20));          // [16,24): k_b / val_b / FC2-pbuf

  const dim3 blk(256);

  trans_cast<<<672, blk, 0, stream>>>(wq, wk, wv, wo, w1, w2,
                                      wqT, wkT, wvT, woT, w1T, w2T, l_all);
  ln_cast_kernel<<<1024, blk, 0, stream>>>(x, ln1s, ln1b, xln);

  for (int b = 0; b < B_; ++b) {
    const __bf16* xln_b = xln + (size_t)b * S_ * D_;
    float* attn_b = attn + (size_t)b * H_ * S_ * S_;
    float* l_b = l_all + (size_t)b * H_ * S_;
    const float* x_b = x + (size_t)b * S_ * D_;
    float* out_b = out + (size_t)b * S_ * D_;

    // merged Q+K: M=2048, N=4096, K=256 -> q in bufA, k in bufA+4M elems (=bufB)
    gemm_nt<6, __bf16><<<dim3(32, 16, 1), blk, 0, stream>>>(
        xln_b, wqT, bq, bk, bufA, 256, 256, 256, 0, 0);

    // scores: P~ = exp(QK^T/16) -> attn_b, row sums -> l_b
    gemm_nt<2, __bf16><<<dim3(16, 16, 8), blk, 0, stream>>>(
        bufA, bufB, nullptr, l_b, attn_b, 256, 256, 256, (long)S_ * E_, (long)S_ * E_);

    // vt_b: (h,e,s) from xln_b (q in bufA dead)
    gemm_nt<1, __bf16><<<dim3(16, 16, 1), blk, 0, stream>>>(
        xln_b, wvT, bv, nullptr, bufA, 256, 256, 256, 0, 0);

    // fused PV: normalize+write attn, val -> bufB (k dead)
    pv_fused<<<dim3(32, 8), blk, 0, stream>>>(attn_b, l_b, bufA, (__bf16*)bufB);

    // WO split-K (kz=4): partials -> bufA (vt dead), then reduce with residual x
    gemm_nt<7, __bf16><<<dim3(2, 16, 4), blk, 0, stream>>>(
        bufB, woT, nullptr, nullptr, (float*)bufA, 512, 2048, 2048, 512, 512);
    reduce_addk<<<512, blk, 0, stream>>>((float*)bufA, x_b, bo, out_b, 131072, 4);
  }

  // ln2 over x2 (held in out region)
  ln_cast_kernel<<<1024, blk, 0, stream>>>(out, ln2s, ln2b, xln);

  // FC1: h = gelu(xln2 @ w1 + b1) : M=4096, N=1024, K=256 -> bufA
  gemm_nt<5, __bf16><<<dim3(8, 32, 1), blk, 0, stream>>>(
      xln, w1T, b1, nullptr, bufA, 256, 256, 256, 0, 0);

  // FC2 split-K (kz=2): partials -> bufB, reduce with residual (in-place on out)
  gemm_nt<7, __bf16><<<dim3(2, 32, 2), blk, 0, stream>>>(
      bufA, w2T, nullptr, nullptr, (float*)bufB, 512, 1024, 1024, 512, 512);
  reduce_addk<<<1024, blk, 0, stream>>>((float*)bufB, out, b2, out, 262144, 2);
}

// Round 5
// 404.360 us; speedup vs baseline: 1.1637x; 1.0645x over previous
//
#include <hip/hip_runtime.h>
#include <hip/hip_bf16.h>

// Problem constants
#define B_ 2
#define S_ 2048
#define D_ 256
#define H_ 8
#define E_ 256
#define F_ 1024

typedef __attribute__((ext_vector_type(8))) __bf16 b16x8;
typedef __attribute__((ext_vector_type(4))) __bf16 b16x4;
typedef __attribute__((ext_vector_type(4))) float f32x4;

__device__ inline float wred_sum(float v) {
#pragma unroll
  for (int o = 32; o > 0; o >>= 1) v += __shfl_xor(v, o);
  return v;
}

// ---------------- LayerNorm (+cast to bf16): one row of 256 per wave ----------------
__global__ __launch_bounds__(256) void ln_cast_kernel(
    const float* __restrict__ x, const float* __restrict__ scale,
    const float* __restrict__ bias, __bf16* __restrict__ out) {
  const int row = blockIdx.x * 4 + (threadIdx.x >> 6);
  const int lane = threadIdx.x & 63;
  const float4 v = *(const float4*)(x + (size_t)row * D_ + lane * 4);
  float s = v.x + v.y + v.z + v.w;
  float q = v.x * v.x + v.y * v.y + v.z * v.z + v.w * v.w;
  s = wred_sum(s);
  q = wred_sum(q);
  const float mean = s * (1.0f / D_);
  const float var = q * (1.0f / D_) - mean * mean;
  const float rstd = rsqrtf(var + 1e-6f);
  const float4 sc = *(const float4*)(scale + lane * 4);
  const float4 bi = *(const float4*)(bias + lane * 4);
  b16x4 o;
  o[0] = (__bf16)((v.x - mean) * rstd * sc.x + bi.x);
  o[1] = (__bf16)((v.y - mean) * rstd * sc.y + bi.y);
  o[2] = (__bf16)((v.z - mean) * rstd * sc.z + bi.z);
  o[3] = (__bf16)((v.w - mean) * rstd * sc.w + bi.w);
  *(b16x4*)(out + (size_t)row * D_ + lane * 4) = o;
}

// ---------------- Weight transpose-cast + l zeroing + bias concat ----------------
// bid<640: 64x64 tiles (wq,wk,wv:128ea; wo:128; w1:64; w2:64)
// bid in [640,672): zero l_all (32768 f32). bid in [672,675): copy bq/bk/bv -> bias_all.
__global__ __launch_bounds__(256) void trans_cast(
    const float* wq, const float* wk, const float* wv, const float* wo,
    const float* w1, const float* w2,
    const float* bq, const float* bk, const float* bv,
    __bf16* wqT, __bf16* wkT, __bf16* wvT, __bf16* woT, __bf16* w1T, __bf16* w2T,
    float* l_all, float* bias_all) {
  __shared__ float lds[64][65];
  int bid = blockIdx.x;
  const int t = threadIdx.x;
  if (bid >= 672) {  // bias concat (3 blocks x 2048 f32)
    const float* src = (bid == 672) ? bq : (bid == 673) ? bk : bv;
    float* dst = bias_all + (bid - 672) * 2048;
    ((float4*)dst)[t] = ((const float4*)src)[t];
    ((float4*)dst)[t + 256] = ((const float4*)src)[t + 256];
    return;
  }
  if (bid >= 640) {  // zero l
    ((float4*)l_all)[(bid - 640) * 256 + t] = float4{0.f, 0.f, 0.f, 0.f};
    return;
  }
  const float* in;
  __bf16* out;
  int R, C, tidx;
  if (bid < 128) { in = wq; out = wqT; R = 256; C = 2048; tidx = bid; }
  else if (bid < 256) { in = wk; out = wkT; R = 256; C = 2048; tidx = bid - 128; }
  else if (bid < 384) { in = wv; out = wvT; R = 256; C = 2048; tidx = bid - 256; }
  else if (bid < 512) { in = wo; out = woT; R = 2048; C = 256; tidx = bid - 384; }
  else if (bid < 576) { in = w1; out = w1T; R = 256; C = 1024; tidx = bid - 512; }
  else { in = w2; out = w2T; R = 1024; C = 256; tidx = bid - 576; }
  const int tiles_c = C >> 6;
  const int tr = tidx / tiles_c, tc = tidx % tiles_c;
  const int r = t >> 2, cq = t & 3;
  const float* base = in + (size_t)(tr * 64 + r) * C + tc * 64 + cq * 16;
#pragma unroll
  for (int i = 0; i < 4; ++i) {
    const float4 v = ((const float4*)base)[i];
    lds[r][cq * 16 + i * 4 + 0] = v.x;
    lds[r][cq * 16 + i * 4 + 1] = v.y;
    lds[r][cq * 16 + i * 4 + 2] = v.z;
    lds[r][cq * 16 + i * 4 + 3] = v.w;
  }
  __syncthreads();
  const int oc = t >> 2;
  __bf16* ob = out + (size_t)(tc * 64 + oc) * R + tr * 64 + cq * 16;
  b16x8 o0, o1;
#pragma unroll
  for (int i = 0; i < 8; ++i) o0[i] = (__bf16)lds[cq * 16 + i][oc];
#pragma unroll
  for (int i = 0; i < 8; ++i) o1[i] = (__bf16)lds[cq * 16 + 8 + i][oc];
  ((b16x8*)ob)[0] = o0;
  ((b16x8*)ob)[1] = o1;
}

__device__ inline float gelu_f(float u) {
  const float c = 0.7978845608028654f;  // sqrt(2/pi)
  float t = tanhf(c * (u + 0.044715f * u * u * u));
  return 0.5f * u * (1.0f + t);
}

// ---------------- NT GEMM: C = A(MxK) * Bt(NxK)^T, bf16 MFMA, fp32 acc ----------------
// BM = MT*32, BN = 128 fixed, BK = 64. 4 waves (2x2).
// EPI: 1=v->(h,e,s)+bias
//      2=scores: write exp(s/16)->f32 + atomicAdd row sums (l in `resid`)
//      5=fc1: gelu(acc+bias)->bf16 (ld F)
//      6=merged qk: sel=gc>>11: 0->q(h,s,e)->Cout, 1->k(h,s,e)->Cout2 (bias_all)
//      7=split-K partial f32 -> pbuf[z][M][256]
#define BN 128
#define BK 64

template <int EPI, int MT, typename TA>
__global__ __launch_bounds__(256) void gemm_nt(
    const TA* __restrict__ A, const __bf16* __restrict__ Bt,
    const float* __restrict__ bias, const float* __restrict__ resid,
    void* __restrict__ Cout, void* __restrict__ Cout2,
    int K, int lda, int ldb, long strideAz, long strideBz) {
  constexpr int BM = MT * 32;
  __shared__ __attribute__((aligned(16))) __bf16 As[BM * BK];
  __shared__ __attribute__((aligned(16))) __bf16 Bs[BN * BK];
  const int tid = threadIdx.x;
  const int lane = tid & 63;
  const int wid = tid >> 6;
  const int wr = wid >> 1, wc = wid & 1;
  const int m0 = blockIdx.y * BM, n0 = blockIdx.x * BN;
  const TA* Ab = A + (size_t)blockIdx.z * strideAz;
  const __bf16* Btb = Bt + (size_t)blockIdx.z * strideBz;

  f32x4 acc[MT][4] = {};

  for (int k0 = 0; k0 < K; k0 += BK) {
    __syncthreads();
#pragma unroll
    for (int i = 0; i < MT; ++i) {
      const int cid = tid + i * 256;
      const int row = cid >> 3, ch = cid & 7;
      const int sw = ch ^ (row & 7);
      b16x8 av;
      const size_t aoff = (size_t)(m0 + row) * lda + k0 + ch * 8;
      if constexpr (sizeof(TA) == 2) {
        av = *(const b16x8*)(Ab + aoff);
      } else {
        const float* ap = (const float*)Ab + aoff;
        const float4 f0 = *(const float4*)ap;
        const float4 f1 = *(const float4*)(ap + 4);
        av[0] = (__bf16)f0.x; av[1] = (__bf16)f0.y;
        av[2] = (__bf16)f0.z; av[3] = (__bf16)f0.w;
        av[4] = (__bf16)f1.x; av[5] = (__bf16)f1.y;
        av[6] = (__bf16)f1.z; av[7] = (__bf16)f1.w;
      }
      *(b16x8*)(As + row * BK + sw * 8) = av;
    }
#pragma unroll
    for (int i = 0; i < 4; ++i) {
      const int cid = tid + i * 256;
      const int row = cid >> 3, ch = cid & 7;
      const int sw = ch ^ (row & 7);
      const b16x8 bv = *(const b16x8*)(Btb + (size_t)(n0 + row) * ldb + k0 + ch * 8);
      *(b16x8*)(Bs + row * BK + sw * 8) = bv;
    }
    __syncthreads();
#pragma unroll
    for (int ks = 0; ks < 2; ++ks) {
      b16x8 af[MT], bfr[4];
#pragma unroll
      for (int m = 0; m < MT; ++m) {
        const int r = wr * (MT * 16) + m * 16 + (lane & 15);
        const int ch = ks * 4 + (lane >> 4);
        af[m] = *(const b16x8*)(As + r * BK + (ch ^ (r & 7)) * 8);
      }
#pragma unroll
      for (int n = 0; n < 4; ++n) {
        const int r = wc * 64 + n * 16 + (lane & 15);
        const int ch = ks * 4 + (lane >> 4);
        bfr[n] = *(const b16x8*)(Bs + r * BK + (ch ^ (r & 7)) * 8);
      }
#pragma unroll
      for (int m = 0; m < MT; ++m)
#pragma unroll
        for (int n = 0; n < 4; ++n)
          acc[m][n] = __builtin_amdgcn_mfma_f32_16x16x32_bf16(af[m], bfr[n],
                                                              acc[m][n], 0, 0, 0);
    }
  }

  const int z = blockIdx.z;

  if constexpr (EPI == 2) {
    float* lrow = const_cast<float*>(resid) + (size_t)z * S_;
    float* ab = (float*)Cout + (size_t)z * S_ * S_;
#pragma unroll
    for (int m = 0; m < MT; ++m) {
#pragma unroll
      for (int r = 0; r < 4; ++r) {
        const int grow = m0 + wr * (MT * 16) + m * 16 + (lane >> 4) * 4 + r;
        float srow = 0.f;
#pragma unroll
        for (int n = 0; n < 4; ++n) {
          const int gc = n0 + wc * 64 + n * 16 + (lane & 15);
          const float p = __expf(acc[m][n][r] * 0.0625f);
          ab[(size_t)grow * S_ + gc] = p;
          srow += p;
        }
        srow += __shfl_xor(srow, 1);
        srow += __shfl_xor(srow, 2);
        srow += __shfl_xor(srow, 4);
        srow += __shfl_xor(srow, 8);
        if ((lane & 15) == 0) atomicAdd(lrow + grow, srow);
      }
    }
    return;
  }

#pragma unroll
  for (int m = 0; m < MT; ++m) {
    const int gr0 = m0 + wr * (MT * 16) + m * 16 + (lane >> 4) * 4;
#pragma unroll
    for (int n = 0; n < 4; ++n) {
      const int gc = n0 + wc * 64 + n * 16 + (lane & 15);
#pragma unroll
      for (int r = 0; r < 4; ++r) {
        float v = acc[m][n][r];
        const int grow = gr0 + r;
        if constexpr (EPI == 1) {
          v += bias[gc];
          const int h = gc >> 8, e = gc & 255;
          ((__bf16*)Cout)[((size_t)h * E_ + e) * S_ + grow] = (__bf16)v;
        } else if constexpr (EPI == 5) {
          ((__bf16*)Cout)[(size_t)grow * F_ + gc] = (__bf16)gelu_f(v + bias[gc]);
        } else if constexpr (EPI == 6) {
          v += bias[gc];
          const int sel = gc >> 11, gcl = gc & 2047;
          const int h = gcl >> 8, e = gcl & 255;
          __bf16* o = sel ? (__bf16*)Cout2 : (__bf16*)Cout;
          o[((size_t)h * S_ + grow) * E_ + e] = (__bf16)v;
        } else {  // 7: split-K partial
          ((float*)Cout)[((size_t)z * gridDim.y * BM + grow) * 256 + gc] = v;
        }
      }
    }
  }
}

// ---------------- Fused PV: normalize P~ in place + write attn + MFMA with V^T ----------------
// Block = 32 q-rows x 256 e-cols (full E -> exclusive row ownership). grid (64, 8).
__global__ __launch_bounds__(256) void pv_fused(
    float* __restrict__ attn_b, const float* __restrict__ l_b,
    const __bf16* __restrict__ vt_b, __bf16* __restrict__ val_b) {
  __shared__ __attribute__((aligned(16))) __bf16 As[32 * 64];    // 4 KB
  __shared__ __attribute__((aligned(16))) __bf16 Bs[256 * 64];   // 32 KB
  const int tid = threadIdx.x, lane = tid & 63, wc = tid >> 6;  // wave tile 32x64
  const int m0 = blockIdx.x * 32;
  const int h = blockIdx.y;
  float* Ab = attn_b + (size_t)h * S_ * S_;
  const float* lb = l_b + (size_t)h * S_;
  const __bf16* Bb = vt_b + (size_t)h * E_ * S_;

  f32x4 acc[2][4] = {};

  for (int k0 = 0; k0 < S_; k0 += 64) {
    __syncthreads();
    // A: 32 rows x 64 cols f32 -> normalize, write back, cast to LDS (1 chunk/thread)
    {
      const int row = tid >> 3, ch = tid & 7;
      float* ap = Ab + (size_t)(m0 + row) * S_ + k0 + ch * 8;
      float4 f0 = ((float4*)ap)[0], f1 = ((float4*)ap)[1];
      const float inv = 1.0f / lb[m0 + row];
      f0.x *= inv; f0.y *= inv; f0.z *= inv; f0.w *= inv;
      f1.x *= inv; f1.y *= inv; f1.z *= inv; f1.w *= inv;
      ((float4*)ap)[0] = f0;
      ((float4*)ap)[1] = f1;
      b16x8 av;
      av[0] = (__bf16)f0.x; av[1] = (__bf16)f0.y;
      av[2] = (__bf16)f0.z; av[3] = (__bf16)f0.w;
      av[4] = (__bf16)f1.x; av[5] = (__bf16)f1.y;
      av[6] = (__bf16)f1.z; av[7] = (__bf16)f1.w;
      const int sw = ch ^ (row & 7);
      *(b16x8*)(As + row * 64 + sw * 8) = av;
    }
    // B: 256 rows x 64 cols bf16
#pragma unroll
    for (int i = 0; i < 8; ++i) {
      const int cid = tid + i * 256;
      const int row = cid >> 3, ch = cid & 7;
      const b16x8 bv = *(const b16x8*)(Bb + (size_t)row * S_ + k0 + ch * 8);
      const int sw = ch ^ (row & 7);
      *(b16x8*)(Bs + row * 64 + sw * 8) = bv;
    }
    __syncthreads();
#pragma unroll
    for (int ks = 0; ks < 2; ++ks) {
      b16x8 af[2], bfr[4];
#pragma unroll
      for (int m = 0; m < 2; ++m) {
        const int r = m * 16 + (lane & 15);
        const int ch = ks * 4 + (lane >> 4);
        af[m] = *(const b16x8*)(As + r * 64 + (ch ^ (r & 7)) * 8);
      }
#pragma unroll
      for (int n = 0; n < 4; ++n) {
        const int r = wc * 64 + n * 16 + (lane & 15);
        const int ch = ks * 4 + (lane >> 4);
        bfr[n] = *(const b16x8*)(Bs + r * 64 + (ch ^ (r & 7)) * 8);
      }
#pragma unroll
      for (int m = 0; m < 2; ++m)
#pragma unroll
        for (int n = 0; n < 4; ++n)
          acc[m][n] = __builtin_amdgcn_mfma_f32_16x16x32_bf16(af[m], bfr[n],
                                                              acc[m][n], 0, 0, 0);
    }
  }

#pragma unroll
  for (int m = 0; m < 2; ++m) {
#pragma unroll
    for (int n = 0; n < 4; ++n) {
#pragma unroll
      for (int r = 0; r < 4; ++r) {
        const int grow = m0 + m * 16 + (lane >> 4) * 4 + r;
        const int gc = wc * 64 + n * 16 + (lane & 15);
        val_b[(size_t)grow * 2048 + h * E_ + gc] = (__bf16)acc[m][n][r];
      }
    }
  }
}

// ---------------- out = resid + bias + sum_z pbuf[z] (N=256 cols) ----------------
__global__ __launch_bounds__(256) void reduce_addk(
    const float* __restrict__ pbuf, const float* __restrict__ resid,
    const float* __restrict__ bias, float* __restrict__ out, int mn4, int kz) {
  const int i = blockIdx.x * 256 + threadIdx.x;
  if (i >= mn4) return;
  float4 s = ((const float4*)resid)[i];
  const float4 bb = ((const float4*)bias)[i & 63];
  s.x += bb.x; s.y += bb.y; s.z += bb.z; s.w += bb.w;
  for (int z = 0; z < kz; ++z) {
    const float4 p = ((const float4*)pbuf)[(size_t)z * mn4 + i];
    s.x += p.x; s.y += p.y; s.z += p.z; s.w += p.w;
  }
  ((float4*)out)[i] = s;
}

extern "C" void kernel_launch(void* const* d_in, const int* in_sizes, int n_in,
                              void* d_out, int out_size, void* d_ws, size_t ws_size,
                              hipStream_t stream) {
  (void)in_sizes; (void)n_in; (void)out_size; (void)ws_size;
  const float* x    = (const float*)d_in[0];
  const float* ln1s = (const float*)d_in[1];
  const float* ln1b = (const float*)d_in[2];
  const float* wq   = (const float*)d_in[3];
  const float* bq   = (const float*)d_in[4];
  const float* wk   = (const float*)d_in[5];
  const float* bk   = (const float*)d_in[6];
  const float* wv   = (const float*)d_in[7];
  const float* bv   = (const float*)d_in[8];
  const float* wo   = (const float*)d_in[9];
  const float* bo   = (const float*)d_in[10];
  const float* ln2s = (const float*)d_in[11];
  const float* ln2b = (const float*)d_in[12];
  const float* w1   = (const float*)d_in[13];
  const float* b1   = (const float*)d_in[14];
  const float* w2   = (const float*)d_in[15];
  const float* b2   = (const float*)d_in[16];

  float* out  = (float*)d_out;                           // (B,S,D), doubles as x2
  float* attn = (float*)d_out + (size_t)B_ * S_ * D_;    // (B,H,S,S) f32

  // ---- workspace: 24 MB total (proven-safe budget) ----
  char* ws = (char*)d_ws;
  __bf16* xln  = (__bf16*)(ws);                          // [0,2MB)
  __bf16* wqT  = (__bf16*)(ws + (2ull << 20));           // [2,3) — wkT contiguous after (merged Q+K B)
  __bf16* wkT  = (__bf16*)(ws + (3ull << 20));           // [3,4)
  __bf16* wvT  = (__bf16*)(ws + (4ull << 20));           // [4,5)
  __bf16* woT  = (__bf16*)(ws + (5ull << 20));           // [5,6)
  __bf16* w1T  = (__bf16*)(ws + (6ull << 20));           // [6,6.5)
  __bf16* w2T  = (__bf16*)(ws + (6ull << 20) + (512ull << 10));  // [6.5,7)
  float*  l_all = (float*)(ws + (7ull << 20));           // [7, +128KB)
  float*  bias_all = (float*)(ws + (7ull << 20) + (128ull << 10));  // +24KB
  __bf16* bufA = (__bf16*)(ws + (8ull << 20));           // [8,16): q -> vt -> WO-partials -> hbf
  __bf16* bufB = (__bf16*)(ws + (16ull << 20));          // [16,24): k -> val -> FC2-partials

  const dim3 blk(256);

  trans_cast<<<675, blk, 0, stream>>>(wq, wk, wv, wo, w1, w2, bq, bk, bv,
                                      wqT, wkT, wvT, woT, w1T, w2T, l_all, bias_all);
  ln_cast_kernel<<<1024, blk, 0, stream>>>(x, ln1s, ln1b, xln);

  for (int b = 0; b < B_; ++b) {
    const __bf16* xln_b = xln + (size_t)b * S_ * D_;
    float* attn_b = attn + (size_t)b * H_ * S_ * S_;
    float* l_b = l_all + (size_t)b * H_ * S_;
    const float* x_b = x + (size_t)b * S_ * D_;
    float* out_b = out + (size_t)b * S_ * D_;

    // merged Q+K: M=2048, N=4096, K=256 -> q(bufA), k(bufB)   [bias_all = bq|bk]
    gemm_nt<6, 4, __bf16><<<dim3(32, 16, 1), blk, 0, stream>>>(
        xln_b, wqT, bias_all, nullptr, bufA, bufB, 256, 256, 256, 0, 0);

    // scores: P~ = exp(QK^T/16) -> attn_b, row sums -> l_b
    gemm_nt<2, 4, __bf16><<<dim3(16, 16, 8), blk, 0, stream>>>(
        bufA, bufB, nullptr, l_b, attn_b, nullptr,
        256, 256, 256, (long)S_ * E_, (long)S_ * E_);

    // vt: (h,e,s) from xln_b -> bufA (q dead after scores)
    gemm_nt<1, 4, __bf16><<<dim3(16, 16, 1), blk, 0, stream>>>(
        xln_b, wvT, bv, nullptr, bufA, nullptr, 256, 256, 256, 0, 0);

    // fused PV: normalize+write attn in place, val -> bufB (k dead)
    pv_fused<<<dim3(64, 8), blk, 0, stream>>>(attn_b, l_b, bufA, (__bf16*)bufB);

    // WO split-K (kz=4, BM=64): partials -> bufA (vt dead), reduce with residual x
    gemm_nt<7, 2, __bf16><<<dim3(2, 32, 4), blk, 0, stream>>>(
        bufB, woT, nullptr, nullptr, (float*)bufA, nullptr,
        512, 2048, 2048, 512, 512);
    reduce_addk<<<512, blk, 0, stream>>>((float*)bufA, x_b, bo, out_b, 131072, 4);
  }

  // ln2 over x2 (held in out region)
  ln_cast_kernel<<<1024, blk, 0, stream>>>(out, ln2s, ln2b, xln);

  // FC1: h = gelu(xln2 @ w1 + b1) : M=4096, N=1024, K=256 -> bufA (BM=64)
  gemm_nt<5, 2, __bf16><<<dim3(8, 64, 1), blk, 0, stream>>>(
      xln, w1T, b1, nullptr, bufA, nullptr, 256, 256, 256, 0, 0);

  // FC2 split-K (kz=2, BM=64): partials -> bufB, reduce with residual (in-place on out)
  gemm_nt<7, 2, __bf16><<<dim3(2, 64, 2), blk, 0, stream>>>(
      bufA, w2T, nullptr, nullptr, (float*)bufB, nullptr,
      512, 1024, 1024, 512, 512);
  reduce_addk<<<1024, blk, 0, stream>>>((float*)bufB, out, b2, out, 262144, 2);
}